// Round 1
// baseline (694.789 us; speedup 1.0000x reference)
//
#include <hip/hip_runtime.h>
#include <cstdint>
#include <cstddef>

// Problem constants (reference: N=16384, DX1=DX2=1024, DH=2048)
#define NR 16384
#define DX 1024
#define DH 2048

typedef unsigned short u16;
typedef _Float16 half8 __attribute__((ext_vector_type(8)));
typedef _Float16 half4v __attribute__((ext_vector_type(4)));
typedef float f32x4 __attribute__((ext_vector_type(4)));

__device__ __forceinline__ u16 f2h_bits(float v) {
    union { _Float16 h; u16 u; } c;
    c.h = (_Float16)v;
    return c.u;
}

// async global->LDS, 16B per lane; LDS dest = wave-uniform base + lane*16
__device__ __forceinline__ void gl_lds16(const void* g, void* l) {
    __builtin_amdgcn_global_load_lds(
        (const __attribute__((address_space(1))) void*)g,
        (__attribute__((address_space(3))) void*)l, 16, 0, 0);
}

// ---------------------------------------------------------------------------
// fp32 -> fp16 elementwise cast (vectorized float4 -> half4). n must be %1024.
__global__ __launch_bounds__(256) void cast_f32_f16(const float* __restrict__ in,
                                                    u16* __restrict__ out) {
    size_t i = ((size_t)blockIdx.x * 256 + threadIdx.x) * 4;
    float4 v = *(const float4*)&in[i];
    half4v o = { (_Float16)v.x, (_Float16)v.y, (_Float16)v.z, (_Float16)v.w };
    *(half4v*)&out[i] = o;
}

// ---------------------------------------------------------------------------
// W [K,D] fp32 -> Wt [D,K] fp16 (LDS tiled transpose). K,D % 32 == 0.
__global__ __launch_bounds__(256) void transpose_cast(const float* __restrict__ in,
                                                      u16* __restrict__ out,
                                                      int K, int D) {
    __shared__ float tile[32][33];
    int tx = threadIdx.x & 31;
    int ty = threadIdx.x >> 5;                  // 0..7
    int d0 = blockIdx.x * 32, k0 = blockIdx.y * 32;
#pragma unroll
    for (int i = 0; i < 32; i += 8)
        tile[ty + i][tx] = in[(size_t)(k0 + ty + i) * D + d0 + tx];
    __syncthreads();
#pragma unroll
    for (int i = 0; i < 32; i += 8)
        out[(size_t)(d0 + ty + i) * K + k0 + tx] = f2h_bits(tile[tx][ty + i]);
}

// ---------------------------------------------------------------------------
// 128x128-tile GEMM, BK=32, 256 threads (4 waves in 2x2), 16x16x32 f16 MFMA.
// A [M,K] fp16 row-major, Bt [N,K] fp16 row-major (i.e. B transposed).
// MODE 0: C[M,N] = A@B + bias   (fp16 out)
// MODE 1: Lacc[row] += sum_col (A@B + bias - Xref)^2   (atomic per row)
template <int MODE>
__global__ __launch_bounds__(256) void gemm_bt(
    const u16* __restrict__ A, const u16* __restrict__ Bt,
    const float* __restrict__ bias,
    u16* __restrict__ C, const float* __restrict__ Xref,
    float* __restrict__ Lacc,
    int M, int N, int K) {
    __shared__ __align__(16) u16 As[128 * 32];
    __shared__ __align__(16) u16 Bs[128 * 32];

    const int tid  = threadIdx.x;
    const int lane = tid & 63;
    const int w    = tid >> 6;
    const int wr   = w >> 1, wc = w & 1;
    const int m0 = blockIdx.x * 128, n0 = blockIdx.y * 128;

    f32x4 acc[4][4] = {};

    // staging addressing: chunk idx covers 512 chunks of 8 halfs (16B)
    const int r0  = tid >> 2;            // 0..63
    const int kc0 = (tid & 3) << 3;      // 0,8,16,24
    const u16* ga0 = A  + (size_t)(m0 + r0)      * K + kc0;
    const u16* ga1 = A  + (size_t)(m0 + r0 + 64) * K + kc0;
    const u16* gb0 = Bt + (size_t)(n0 + r0)      * K + kc0;
    const u16* gb1 = Bt + (size_t)(n0 + r0 + 64) * K + kc0;
    u16* lA0 = &As[(tid & ~63) * 8];
    u16* lA1 = &As[(tid & ~63) * 8 + 2048];
    u16* lB0 = &Bs[(tid & ~63) * 8];
    u16* lB1 = &Bs[(tid & ~63) * 8 + 2048];

    const int qa = (lane >> 4) * 8;      // k-offset of this lane's fragment
    const int fr = lane & 15;            // row (A) / col (B) within 16-tile

    for (int kt = 0; kt < K; kt += 32) {
        gl_lds16(ga0 + kt, lA0);
        gl_lds16(ga1 + kt, lA1);
        gl_lds16(gb0 + kt, lB0);
        gl_lds16(gb1 + kt, lB1);
        __syncthreads();   // compiler emits s_waitcnt vmcnt(0) before s_barrier

        half8 af[4], bf[4];
#pragma unroll
        for (int i = 0; i < 4; ++i) {
            af[i] = *(const half8*)&As[(wr * 64 + i * 16 + fr) * 32 + qa];
            bf[i] = *(const half8*)&Bs[(wc * 64 + i * 16 + fr) * 32 + qa];
        }
#pragma unroll
        for (int i = 0; i < 4; ++i)
#pragma unroll
            for (int j = 0; j < 4; ++j)
                acc[i][j] = __builtin_amdgcn_mfma_f32_16x16x32_f16(
                    af[i], bf[j], acc[i][j], 0, 0, 0);
        __syncthreads();
    }

    // epilogue: C/D layout col = lane&15, row = (lane>>4)*4 + reg  [m89/m91]
    const int colbase = n0 + wc * 64 + fr;
    float bj[4];
#pragma unroll
    for (int j = 0; j < 4; ++j) bj[j] = bias[colbase + j * 16];

    if (MODE == 0) {
#pragma unroll
        for (int i = 0; i < 4; ++i) {
            int rowb = m0 + wr * 64 + i * 16 + (lane >> 4) * 4;
#pragma unroll
            for (int r = 0; r < 4; ++r) {
                size_t ro = (size_t)(rowb + r) * N;
#pragma unroll
                for (int j = 0; j < 4; ++j)
                    C[ro + colbase + j * 16] = f2h_bits(acc[i][j][r] + bj[j]);
            }
        }
    } else {
#pragma unroll
        for (int i = 0; i < 4; ++i) {
            int rowb = m0 + wr * 64 + i * 16 + (lane >> 4) * 4;
#pragma unroll
            for (int r = 0; r < 4; ++r) {
                size_t ro = (size_t)(rowb + r) * N;
                float s = 0.f;
#pragma unroll
                for (int j = 0; j < 4; ++j) {
                    float d = acc[i][j][r] + bj[j] - Xref[ro + colbase + j * 16];
                    s += d * d;
                }
                // reduce over the 16 lanes sharing this row (cols)
                s += __shfl_xor(s, 1, 64);
                s += __shfl_xor(s, 2, 64);
                s += __shfl_xor(s, 4, 64);
                s += __shfl_xor(s, 8, 64);
                if (fr == 0) atomicAdd(&Lacc[rowb + r], s);
            }
        }
    }
}

// ---------------------------------------------------------------------------
// Per-row L3 = sum (h1-h2)^2 and L4row = sum (h1+h2)*whoW. One block per row.
__global__ __launch_bounds__(256) void l34_kernel(
    const u16* __restrict__ H1, const u16* __restrict__ H2,
    const float* __restrict__ whoW,
    float* __restrict__ L3, float* __restrict__ L4) {
    int row = blockIdx.x;
    int tid = threadIdx.x;
    const half8 h1 = *(const half8*)&H1[(size_t)row * DH + tid * 8];
    const half8 h2 = *(const half8*)&H2[(size_t)row * DH + tid * 8];
    float4 w0 = *(const float4*)&whoW[tid * 8];
    float4 w1 = *(const float4*)&whoW[tid * 8 + 4];
    float wv[8] = { w0.x, w0.y, w0.z, w0.w, w1.x, w1.y, w1.z, w1.w };
    float s3 = 0.f, s4 = 0.f;
#pragma unroll
    for (int u = 0; u < 8; ++u) {
        float a = (float)h1[u], b = (float)h2[u];
        float d = a - b;
        s3 += d * d;
        s4 += (a + b) * wv[u];
    }
#pragma unroll
    for (int off = 1; off < 64; off <<= 1) {
        s3 += __shfl_xor(s3, off, 64);
        s4 += __shfl_xor(s4, off, 64);
    }
    __shared__ float sm[8];
    int wvi = tid >> 6, ln = tid & 63;
    if (ln == 0) { sm[wvi] = s3; sm[4 + wvi] = s4; }
    __syncthreads();
    if (tid == 0) {
        L3[row] = sm[0] + sm[1] + sm[2] + sm[3];
        L4[row] = sm[4] + sm[5] + sm[6] + sm[7];
    }
}

// ---------------------------------------------------------------------------
// loss = sum_r L1^2 + L2^2 + L3^2 + (0.5*(L4row + who_b) - Y)^2
__global__ __launch_bounds__(1024) void final_reduce(
    const float* __restrict__ L1, const float* __restrict__ L2,
    const float* __restrict__ L3, const float* __restrict__ L4,
    const float* __restrict__ Y, const float* __restrict__ whob,
    float* __restrict__ out) {
    float s = 0.f;
    float wb = whob[0];
    for (int r = threadIdx.x; r < NR; r += 1024) {
        float l4 = 0.5f * (L4[r] + wb) - Y[r];
        s += L1[r] * L1[r] + L2[r] * L2[r] + L3[r] * L3[r] + l4 * l4;
    }
#pragma unroll
    for (int off = 1; off < 64; off <<= 1) s += __shfl_xor(s, off, 64);
    __shared__ float sm[16];
    int w = threadIdx.x >> 6, ln = threadIdx.x & 63;
    if (ln == 0) sm[w] = s;
    __syncthreads();
    if (threadIdx.x == 0) {
        float t = 0.f;
#pragma unroll
        for (int i = 0; i < 16; ++i) t += sm[i];
        out[0] = t;
    }
}

// ---------------------------------------------------------------------------
extern "C" void kernel_launch(void* const* d_in, const int* in_sizes, int n_in,
                              void* d_out, int out_size, void* d_ws, size_t ws_size,
                              hipStream_t stream) {
    const float* X1   = (const float*)d_in[0];
    const float* X2   = (const float*)d_in[1];
    const float* Y    = (const float*)d_in[2];
    const float* w1hW = (const float*)d_in[3];
    const float* w1hb = (const float*)d_in[4];
    const float* w2hW = (const float*)d_in[5];
    const float* w2hb = (const float*)d_in[6];
    const float* wh1W = (const float*)d_in[7];
    const float* wh1b = (const float*)d_in[8];
    const float* wh2W = (const float*)d_in[9];
    const float* wh2b = (const float*)d_in[10];
    const float* whoW = (const float*)d_in[11];
    const float* whob = (const float*)d_in[12];

    // workspace layout (~208.3 MB total)
    char* ws = (char*)d_ws;
    u16* X1h  = (u16*)(ws);                               // 16384x1024 fp16
    u16* X2h  = X1h + (size_t)NR * DX;
    u16* H1h  = X2h + (size_t)NR * DX;                    // 16384x2048 fp16
    u16* H2h  = H1h + (size_t)NR * DH;
    u16* w1hT = H2h + (size_t)NR * DH;                    // [DH][DX]
    u16* w2hT = w1hT + (size_t)DH * DX;
    u16* wh1T = w2hT + (size_t)DH * DX;                   // [DX][DH]
    u16* wh2T = wh1T + (size_t)DX * DH;
    float* L1a = (float*)(wh2T + (size_t)DX * DH);        // 4 x 16384 f32
    float* L2a = L1a + NR;
    float* L3a = L2a + NR;
    float* L4a = L3a + NR;

    // zero the atomically-accumulated arrays (ws is poisoned 0xAA each call)
    hipMemsetAsync(L1a, 0, 2 * (size_t)NR * sizeof(float), stream);

    // casts
    cast_f32_f16<<<NR * DX / 1024, 256, 0, stream>>>(X1, X1h);
    cast_f32_f16<<<NR * DX / 1024, 256, 0, stream>>>(X2, X2h);
    transpose_cast<<<dim3(DH / 32, DX / 32), 256, 0, stream>>>(w1hW, w1hT, DX, DH);
    transpose_cast<<<dim3(DH / 32, DX / 32), 256, 0, stream>>>(w2hW, w2hT, DX, DH);
    transpose_cast<<<dim3(DX / 32, DH / 32), 256, 0, stream>>>(wh1W, wh1T, DH, DX);
    transpose_cast<<<dim3(DX / 32, DH / 32), 256, 0, stream>>>(wh2W, wh2T, DH, DX);

    // H1 = X1@w1h + b, H2 = X2@w2h + b  (fp16 out)
    gemm_bt<0><<<dim3(NR / 128, DH / 128), 256, 0, stream>>>(
        X1h, w1hT, w1hb, H1h, nullptr, nullptr, NR, DH, DX);
    gemm_bt<0><<<dim3(NR / 128, DH / 128), 256, 0, stream>>>(
        X2h, w2hT, w2hb, H2h, nullptr, nullptr, NR, DH, DX);

    // L3, L4row from H1, H2
    l34_kernel<<<NR, 256, 0, stream>>>(H1h, H2h, whoW, L3a, L4a);

    // L1 = rowsq(H1@wh2 + b - X2), L2 = rowsq(H2@wh1 + b - X1)
    gemm_bt<1><<<dim3(NR / 128, DX / 128), 256, 0, stream>>>(
        H1h, wh2T, wh2b, nullptr, X2, L1a, NR, DX, DH);
    gemm_bt<1><<<dim3(NR / 128, DX / 128), 256, 0, stream>>>(
        H2h, wh1T, wh1b, nullptr, X1, L2a, NR, DX, DH);

    final_reduce<<<1, 1024, 0, stream>>>(L1a, L2a, L3a, L4a, Y, whob, (float*)d_out);
}